// Round 7
// baseline (245.512 us; speedup 1.0000x reference)
//
#include <hip/hip_runtime.h>
#include <hip/hip_bf16.h>

typedef __attribute__((ext_vector_type(8))) short short8;
typedef __attribute__((ext_vector_type(4))) float f32x4;

#define B_N 1024
#define D_K 512
#define C_N 100000
#define SCALE_F 64.0f
#define MARGIN_F 0.35f
#define MAXL 64.0f   // global logit bound: |cos|*64 <= 64
#define BMT 256
#define BNT 256
#define NTILN 391    // ceil(100000/256)
#define NWG 1564     // 4 * 391

__device__ __forceinline__ float dot4(float4 a, float4 b) {
    return a.x * b.x + a.y * b.y + a.z * b.z + a.w * b.w;
}

// round-to-nearest-even f32 -> bf16 bits
__device__ __forceinline__ ushort f2b(float f) {
    unsigned int u = __float_as_uint(f);
    u = (u + 0x7FFFu + ((u >> 16) & 1u)) >> 16;
    return (ushort)u;
}

// ---------------- kernel A: normalize x rows -> bf16 ----------------
__global__ void norm_x_kernel(const float* __restrict__ x,
                              ushort* __restrict__ xnb) {
    int row = blockIdx.x * 4 + (threadIdx.x >> 6);
    int l = threadIdx.x & 63;
    const float4* rp = (const float4*)(x + (size_t)row * D_K);
    float4 a = rp[l], b = rp[64 + l];
    float ssq = dot4(a, a) + dot4(b, b);
#pragma unroll
    for (int m = 1; m < 64; m <<= 1) ssq += __shfl_xor(ssq, m);
    float inv = 1.0f / fmaxf(sqrtf(ssq), 1e-12f);
    a.x *= inv; a.y *= inv; a.z *= inv; a.w *= inv;
    b.x *= inv; b.y *= inv; b.z *= inv; b.w *= inv;
    ushort4 ua; ua.x = f2b(a.x); ua.y = f2b(a.y); ua.z = f2b(a.z); ua.w = f2b(a.w);
    ushort4 ub; ub.x = f2b(b.x); ub.y = f2b(b.y); ub.z = f2b(b.z); ub.w = f2b(b.w);
    ushort4* obp = (ushort4*)(xnb + (size_t)row * D_K);
    obp[l] = ua; obp[64 + l] = ub;
}

// ---------------- kernel B: normalize id_agent rows -> bf16 ----------------
__global__ void norm_w_kernel(const float* __restrict__ w,
                              ushort* __restrict__ wb) {
    int row = blockIdx.x * 4 + (threadIdx.x >> 6);
    int l = threadIdx.x & 63;
    const float4* rp = (const float4*)(w + (size_t)row * D_K);
    float4 a = rp[l], b = rp[64 + l];
    float ssq = dot4(a, a) + dot4(b, b);
#pragma unroll
    for (int m = 1; m < 64; m <<= 1) ssq += __shfl_xor(ssq, m);
    float inv = 1.0f / fmaxf(sqrtf(ssq), 1e-12f);
    a.x *= inv; a.y *= inv; a.z *= inv; a.w *= inv;
    b.x *= inv; b.y *= inv; b.z *= inv; b.w *= inv;
    ushort4 ua; ua.x = f2b(a.x); ua.y = f2b(a.y); ua.z = f2b(a.z); ua.w = f2b(a.w);
    ushort4 ub; ub.x = f2b(b.x); ub.y = f2b(b.y); ub.z = f2b(b.z); ub.w = f2b(b.w);
    ushort4* obp = (ushort4*)(wb + (size_t)row * D_K);
    obp[l] = ua; obp[64 + l] = ub;
}

// ------------- kernel C: disc loss partial + exact target logit -------------
__global__ void disc_kernel(const float* __restrict__ x,
                            const int* __restrict__ target,
                            const float* __restrict__ ida,
                            const float* __restrict__ bmat,
                            float* __restrict__ sums,
                            float* __restrict__ tlogit) {
    int row = blockIdx.x * 4 + (threadIdx.x >> 6);
    int l = threadIdx.x & 63;
    long t = (long)target[row];
    const float4* xp = (const float4*)(x + (size_t)row * D_K);
    const float4* wp = (const float4*)(ida + (size_t)t * D_K);
    const float4* bp = (const float4*)(bmat + (size_t)t * D_K);
    float4 x0 = xp[l], x1 = xp[64 + l];
    float4 w0 = wp[l], w1 = wp[64 + l];
    float4 b0 = bp[l], b1 = bp[64 + l];
    float xssq = dot4(x0, x0) + dot4(x1, x1);
    float wssq = dot4(w0, w0) + dot4(w1, w1);
    float bssq = dot4(b0, b0) + dot4(b1, b1);
#pragma unroll
    for (int m = 1; m < 64; m <<= 1) {
        xssq += __shfl_xor(xssq, m);
        wssq += __shfl_xor(wssq, m);
        bssq += __shfl_xor(bssq, m);
    }
    float xinv = 1.0f / fmaxf(sqrtf(xssq), 1e-12f);
    float winv = 1.0f / fmaxf(sqrtf(wssq), 1e-12f);
    float btn = sqrtf(bssq);
    float cs = fminf(btn, 0.05f) / fmaxf(btn, 1e-12f);

    float xs[8] = {x0.x, x0.y, x0.z, x0.w, x1.x, x1.y, x1.z, x1.w};
    float wv[8] = {w0.x, w0.y, w0.z, w0.w, w1.x, w1.y, w1.z, w1.w};
    float bv[8] = {b0.x, b0.y, b0.z, b0.w, b1.x, b1.y, b1.z, b1.w};
    float rss = 0.0f, dt = 0.0f;
#pragma unroll
    for (int i = 0; i < 8; ++i) {
        float xn = xs[i] * xinv;
        float wn = wv[i] * winv;
        float d = xn - wn;
        float r = d - bv[i] * cs;
        rss += r * r;
        dt += xn * wn;
    }
#pragma unroll
    for (int m = 1; m < 64; m <<= 1) {
        rss += __shfl_xor(rss, m);
        dt += __shfl_xor(dt, m);
    }
    if (l == 0) {
        atomicAdd(&sums[0], sqrtf(rss));
        tlogit[row] = SCALE_F * dt;
    }
}

// ------------- kernel D: 256x256 bf16 MFMA GEMM, 8-phase (C-quadrant) schedule,
//               counted vmcnt (sound: vmcnt -> barrier), XOR-swizzled LDS,
//               fused fixed-max sumexp epilogue -------------
__global__ __launch_bounds__(512, 2) void gemm_lse_kernel(const ushort* __restrict__ A,
                                                          const ushort* __restrict__ W,
                                                          float* __restrict__ rowsum) {
    // 2 bufs x 2 halves x [128 rows][64 k] bf16 each (16 KB/half); 8 16B-slots/row,
    // phys_slot = logical_slot ^ (row&7)  (R4's measured-zero-conflict scheme)
    __shared__ ushort Asl[32768];   // 64 KB
    __shared__ ushort Bsl[32768];   // 64 KB
    __shared__ float rs[4][256];    // 4 KB epilogue

    int tid = threadIdx.x;
    int wave = tid >> 6, l = tid & 63;
    int wm = wave >> 2, wn = wave & 3;       // 2 M-waves x 4 N-waves
    int cl = l & 15, hi = l >> 4;

    // XCD-bijective swizzle (nwg=1564: q=195, r=4), mt-minor.
    int orig = blockIdx.x;
    int xcd = orig & 7, idx = orig >> 3;
    const int q = NWG >> 3, r = NWG & 7;
    int wgid = (xcd < r ? xcd * (q + 1) : r * (q + 1) + (xcd - r) * q) + idx;
    int nt = wgid >> 2, mt = wgid & 3;
    int m0 = mt * BMT, n0 = nt * BNT;

    // ---- staging constants: per wave 2 chunks of 1KB per half-tile ----
    // lane l -> row wave*16 + c*8 + (l>>3), phys slot l&7, source slot (l&7)^(l>>3)
    int l8 = l >> 3, l7 = l & 7;
    int sslot = l7 ^ l8;
    const ushort* aS0 = A + (size_t)(m0 + wave * 16 + l8) * D_K + sslot * 8;
    const ushort* aS1 = aS0 + 128 * D_K;
    int q0 = n0 + wave * 16 + l8;
    int q1 = q0 + 8, q2 = q0 + 128, q3 = q0 + 136;
    q0 = q0 < C_N ? q0 : C_N - 1; q1 = q1 < C_N ? q1 : C_N - 1;
    q2 = q2 < C_N ? q2 : C_N - 1; q3 = q3 < C_N ? q3 : C_N - 1;
    const ushort* bS00 = W + (size_t)q0 * D_K + sslot * 8;
    const ushort* bS01 = W + (size_t)q1 * D_K + sslot * 8;
    const ushort* bS10 = W + (size_t)q2 * D_K + sslot * 8;
    const ushort* bS11 = W + (size_t)q3 * D_K + sslot * 8;
    int sdst = wave * 1024;            // ushort idx within a half; chunk1 = +512

    // ---- ds_read constants: slot(kk) = (4kk+hi)^(cl&7); kk=1 is ^32 on ushort idx ----
    int slotk0 = (((cl >> 2) & 1) * 4 + (hi ^ (cl & 3))) * 8;
    int aRB = (wm * 64 + cl) * 64 + slotk0;
    int aRBx = aRB ^ 32;
    int bRB = (wn * 32 + cl) * 64 + slotk0;
    int bRBx = bRB ^ 32;

    f32x4 acc[2][4][2][2];
#pragma unroll
    for (int a = 0; a < 2; ++a)
#pragma unroll
        for (int b = 0; b < 4; ++b)
#pragma unroll
            for (int c = 0; c < 2; ++c)
#pragma unroll
                for (int d = 0; d < 2; ++d) acc[a][b][c][d] = (f32x4){0.f, 0.f, 0.f, 0.f};

#define GLL(SRC, DST) __builtin_amdgcn_global_load_lds(                          \
        (const __attribute__((address_space(1))) void*)(SRC),                    \
        (__attribute__((address_space(3))) void*)(DST), 16, 0, 0)
#define STGA(T1, MH) do { int ko_ = (T1) * 64;                                   \
    int bo_ = ((T1) & 1) * 16384 + (MH) * 8192 + sdst;                           \
    const ushort* s_ = (MH) ? aS1 : aS0;                                         \
    GLL(s_ + ko_, &Asl[bo_]); GLL(s_ + ko_ + 4096, &Asl[bo_ + 512]); } while (0)
#define STGB(T1, NH) do { int ko_ = (T1) * 64;                                   \
    int bo_ = ((T1) & 1) * 16384 + (NH) * 8192 + sdst;                           \
    GLL(((NH) ? bS10 : bS00) + ko_, &Bsl[bo_]);                                  \
    GLL(((NH) ? bS11 : bS01) + ko_, &Bsl[bo_ + 512]); } while (0)
#define RDA(P, CB, MH) do { const ushort* p_ = &Asl[(CB) + (MH) * 8192];         \
    P##0 = *(const short8*)&p_[aRB];        P##1 = *(const short8*)&p_[aRB + 1024];  \
    P##2 = *(const short8*)&p_[aRB + 2048]; P##3 = *(const short8*)&p_[aRB + 3072]; \
    P##4 = *(const short8*)&p_[aRBx];       P##5 = *(const short8*)&p_[aRBx + 1024]; \
    P##6 = *(const short8*)&p_[aRBx + 2048];P##7 = *(const short8*)&p_[aRBx + 3072]; } while (0)
#define RDB(P, CB, NH) do { const ushort* p_ = &Bsl[(CB) + (NH) * 8192];         \
    P##0 = *(const short8*)&p_[bRB];  P##1 = *(const short8*)&p_[bRB + 1024];    \
    P##2 = *(const short8*)&p_[bRBx]; P##3 = *(const short8*)&p_[bRBx + 1024]; } while (0)
#define MFMA1(D, Aa, Bb) D = __builtin_amdgcn_mfma_f32_16x16x32_bf16(Aa, Bb, D, 0, 0, 0)
#define M16(MH, NH, A_, B_) do {                                                 \
    MFMA1(acc[MH][0][NH][0], A_##0, B_##0); MFMA1(acc[MH][0][NH][1], A_##0, B_##1); \
    MFMA1(acc[MH][1][NH][0], A_##1, B_##0); MFMA1(acc[MH][1][NH][1], A_##1, B_##1); \
    MFMA1(acc[MH][2][NH][0], A_##2, B_##0); MFMA1(acc[MH][2][NH][1], A_##2, B_##1); \
    MFMA1(acc[MH][3][NH][0], A_##3, B_##0); MFMA1(acc[MH][3][NH][1], A_##3, B_##1); \
    MFMA1(acc[MH][0][NH][0], A_##4, B_##2); MFMA1(acc[MH][0][NH][1], A_##4, B_##3); \
    MFMA1(acc[MH][1][NH][0], A_##5, B_##2); MFMA1(acc[MH][1][NH][1], A_##5, B_##3); \
    MFMA1(acc[MH][2][NH][0], A_##6, B_##2); MFMA1(acc[MH][2][NH][1], A_##6, B_##3); \
    MFMA1(acc[MH][3][NH][0], A_##7, B_##2); MFMA1(acc[MH][3][NH][1], A_##7, B_##3); } while (0)
#define LGKM0 do { asm volatile("s_waitcnt lgkmcnt(0)" ::: "memory");            \
                   __builtin_amdgcn_sched_barrier(0); } while (0)
#define BAR __builtin_amdgcn_s_barrier()
#define PRIO1 __builtin_amdgcn_s_setprio(1)
#define PRIO0 __builtin_amdgcn_s_setprio(0)

    // prologue: stage tile 0 halves in use-order A0,B0,A1,B1; wait first two
    STGA(0, 0); STGB(0, 0); STGA(0, 1); STGB(0, 1);
    asm volatile("s_waitcnt vmcnt(4)" ::: "memory");
    BAR;

    for (int t = 0; t < 7; ++t) {
        int cb = (t & 1) * 16384;
        short8 af0, af1, af2, af3, af4, af5, af6, af7;
        short8 ag0, ag1, ag2, ag3, ag4, ag5, ag6, ag7;
        short8 bf0, bf1, bf2, bf3, bg0, bg1, bg2, bg3;
        // P1: (mh0, nh0) — reads A0,B0; stages A0(t+1)
        RDA(af, cb, 0); RDB(bf, cb, 0);
        STGA(t + 1, 0);
        BAR; LGKM0; PRIO1; M16(0, 0, af, bf); PRIO0;
        asm volatile("s_waitcnt vmcnt(4)" ::: "memory");   // A1(t) landed
        BAR;
        // P2: (mh1, nh0) — reads A1, reuses B0; stages B0(t+1)
        RDA(ag, cb, 1);
        STGB(t + 1, 0);
        BAR; LGKM0; PRIO1; M16(1, 0, ag, bf); PRIO0;
        asm volatile("s_waitcnt vmcnt(4)" ::: "memory");   // B1(t) landed
        BAR;
        // P3: (mh1, nh1) — reads B1, reuses A1; stages A1(t+1)
        RDB(bg, cb, 1);
        STGA(t + 1, 1);
        BAR; LGKM0; PRIO1; M16(1, 1, ag, bg); PRIO0;
        BAR;
        // P4: (mh0, nh1) — re-reads A0, reuses B1; stages B1(t+1)
        RDA(af, cb, 0);
        STGB(t + 1, 1);
        BAR; LGKM0; PRIO1; M16(0, 1, af, bg); PRIO0;
        asm volatile("s_waitcnt vmcnt(4)" ::: "memory");   // A0,B0(t+1) landed
        BAR;
    }
    {   // t = 7 tail: no staging
        int cb = 16384;
        short8 af0, af1, af2, af3, af4, af5, af6, af7;
        short8 ag0, ag1, ag2, ag3, ag4, ag5, ag6, ag7;
        short8 bf0, bf1, bf2, bf3, bg0, bg1, bg2, bg3;
        RDA(af, cb, 0); RDB(bf, cb, 0);
        BAR; LGKM0; PRIO1; M16(0, 0, af, bf); PRIO0;
        asm volatile("s_waitcnt vmcnt(2)" ::: "memory");
        BAR;
        RDA(ag, cb, 1);
        BAR; LGKM0; PRIO1; M16(1, 0, ag, bf); PRIO0;
        asm volatile("s_waitcnt vmcnt(0)" ::: "memory");
        BAR;
        RDB(bg, cb, 1);
        BAR; LGKM0; PRIO1; M16(1, 1, ag, bg); PRIO0;
        BAR;
        RDA(af, cb, 0);
        BAR; LGKM0; PRIO1; M16(0, 1, af, bg); PRIO0;
        BAR;
    }

    // ---- epilogue: per-row sum of exp(s - 64), fixed global max (s <= 64) ----
#pragma unroll
    for (int mh = 0; mh < 2; ++mh)
#pragma unroll
        for (int mi = 0; mi < 4; ++mi)
#pragma unroll
            for (int j = 0; j < 4; ++j) {
                float se = 0.0f;
#pragma unroll
                for (int nh = 0; nh < 2; ++nh)
#pragma unroll
                    for (int ni = 0; ni < 2; ++ni) {
                        int cg = n0 + nh * 128 + wn * 32 + ni * 16 + cl;
                        if (cg < C_N) se += __expf(acc[mh][mi][nh][ni][j] * SCALE_F - MAXL);
                    }
#pragma unroll
                for (int xm = 1; xm < 16; xm <<= 1) se += __shfl_xor(se, xm);
                if (cl == 0) rs[wn][mh * 128 + wm * 64 + mi * 16 + hi * 4 + j] = se;
            }
    __syncthreads();
    if (tid < 256) {
        float s = rs[0][tid] + rs[1][tid] + rs[2][tid] + rs[3][tid];
        atomicAdd(&rowsum[m0 + tid], s);
    }
#undef GLL
#undef STGA
#undef STGB
#undef RDA
#undef RDB
#undef MFMA1
#undef M16
#undef LGKM0
#undef BAR
#undef PRIO1
#undef PRIO0
}

// ------------- kernel E: per-row lse from fixed-max sumexp -> nll -> sums[1] -------------
__global__ void rowfin_kernel(const float* __restrict__ rowsum,
                              const float* __restrict__ tlogit,
                              float* __restrict__ sums) {
    __shared__ float red[4];
    int tid = threadIdx.x;
    int row = blockIdx.x * 256 + tid;
    float lse = MAXL + logf(rowsum[row]);
    float st = tlogit[row];
    // replace exp(st) by exp(st - 64*margin) inside the lse
    float corr = __expf(st - lse) * (__expf(-SCALE_F * MARGIN_F) - 1.0f);
    float lse2 = lse + log1pf(corr);
    float nll = lse2 - (st - SCALE_F * MARGIN_F);
#pragma unroll
    for (int xm = 1; xm < 64; xm <<= 1) nll += __shfl_xor(nll, xm);
    if ((tid & 63) == 0) red[tid >> 6] = nll;
    __syncthreads();
    if (tid == 0) atomicAdd(&sums[1], red[0] + red[1] + red[2] + red[3]);
}

// ------------- kernel F: finalize scalar output -------------
__global__ void finalize_kernel(const float* __restrict__ sums, float* __restrict__ out) {
    float disc = sums[0] * (1.0f / B_N);
    float logp = sums[1] * (1.0f / B_N);
    float p = __expf(-logp);
    float om = 1.0f - p;
    out[0] = 0.4f * disc + om * om * logp;
}

extern "C" void kernel_launch(void* const* d_in, const int* in_sizes, int n_in,
                              void* d_out, int out_size, void* d_ws, size_t ws_size,
                              hipStream_t stream) {
    const float* x = (const float*)d_in[0];
    const int* target = (const int*)d_in[1];
    const float* ida = (const float*)d_in[2];
    const float* bmat = (const float*)d_in[3];
    float* out = (float*)d_out;

    char* ws = (char*)d_ws;
    size_t off = 0;
    float* rowsum = (float*)(ws + off);  off += (size_t)B_N * 4;         // 4 KB
    float* sums = (float*)(ws + off);    off += 256;
    ushort* xnb = (ushort*)(ws + off);   off += (size_t)B_N * D_K * 2;   // 1 MB
    ushort* wbf = (ushort*)(ws + off);   off += (size_t)C_N * D_K * 2;   // 102.4 MB
    float* tlogit = (float*)(ws + off);  off += (size_t)B_N * 4;

    // zero rowsum + sums (contiguous region) every call — deterministic
    hipMemsetAsync(rowsum, 0, (size_t)B_N * 4 + 256, stream);

    norm_x_kernel<<<B_N / 4, 256, 0, stream>>>(x, xnb);
    norm_w_kernel<<<C_N / 4, 256, 0, stream>>>(ida, wbf);
    disc_kernel<<<B_N / 4, 256, 0, stream>>>(x, target, ida, bmat, sums, tlogit);
    gemm_lse_kernel<<<NWG, 512, 0, stream>>>(xnb, wbf, rowsum);
    rowfin_kernel<<<B_N / 256, 256, 0, stream>>>(rowsum, tlogit, sums);
    finalize_kernel<<<1, 1, 0, stream>>>(sums, out);
}

// Round 8
// 193.649 us; speedup vs baseline: 1.2678x; 1.2678x over previous
//
#include <hip/hip_runtime.h>
#include <hip/hip_bf16.h>

typedef __attribute__((ext_vector_type(8))) short short8;
typedef __attribute__((ext_vector_type(4))) float f32x4;

#define B_N 1024
#define D_K 512
#define C_N 100000
#define SCALE_F 64.0f
#define MARGIN_F 0.35f
#define BM 128
#define BN 128
#define BK 64
#define NT_ 782   // ceil(100000/128)
#define MT_ 8     // 1024/128
#define MAXL 64.0f   // global logit bound: |cos|*64 <= 64

__device__ __forceinline__ float dot4(float4 a, float4 b) {
    return a.x * b.x + a.y * b.y + a.z * b.z + a.w * b.w;
}

// round-to-nearest-even f32 -> bf16 bits
__device__ __forceinline__ ushort f2b(float f) {
    unsigned int u = __float_as_uint(f);
    u = (u + 0x7FFFu + ((u >> 16) & 1u)) >> 16;
    return (ushort)u;
}

// ------------- kernel A: fused norm_x (write bf16) + disc loss + target logit -------------
__global__ void normx_disc_kernel(const float* __restrict__ x,
                                  const int* __restrict__ target,
                                  const float* __restrict__ ida,
                                  const float* __restrict__ bmat,
                                  ushort* __restrict__ xnb,
                                  float* __restrict__ sums,
                                  float* __restrict__ tlogit) {
    int row = blockIdx.x * 4 + (threadIdx.x >> 6);
    int l = threadIdx.x & 63;
    long t = (long)target[row];
    const float4* xp = (const float4*)(x + (size_t)row * D_K);
    const float4* wp = (const float4*)(ida + (size_t)t * D_K);
    const float4* bp = (const float4*)(bmat + (size_t)t * D_K);
    float4 x0 = xp[l], x1 = xp[64 + l];
    float4 w0 = wp[l], w1 = wp[64 + l];
    float4 b0 = bp[l], b1 = bp[64 + l];
    float xssq = dot4(x0, x0) + dot4(x1, x1);
    float wssq = dot4(w0, w0) + dot4(w1, w1);
    float bssq = dot4(b0, b0) + dot4(b1, b1);
#pragma unroll
    for (int m = 1; m < 64; m <<= 1) {
        xssq += __shfl_xor(xssq, m);
        wssq += __shfl_xor(wssq, m);
        bssq += __shfl_xor(bssq, m);
    }
    float xinv = 1.0f / fmaxf(sqrtf(xssq), 1e-12f);
    float winv = 1.0f / fmaxf(sqrtf(wssq), 1e-12f);
    float btn = sqrtf(bssq);
    float cs = fminf(btn, 0.05f) / fmaxf(btn, 1e-12f);

    // write normalized x as bf16 (for the GEMM A operand)
    {
        float4 a = x0, b = x1;
        a.x *= xinv; a.y *= xinv; a.z *= xinv; a.w *= xinv;
        b.x *= xinv; b.y *= xinv; b.z *= xinv; b.w *= xinv;
        ushort4 ua; ua.x = f2b(a.x); ua.y = f2b(a.y); ua.z = f2b(a.z); ua.w = f2b(a.w);
        ushort4 ub; ub.x = f2b(b.x); ub.y = f2b(b.y); ub.z = f2b(b.z); ub.w = f2b(b.w);
        ushort4* obp = (ushort4*)(xnb + (size_t)row * D_K);
        obp[l] = ua; obp[64 + l] = ub;
    }

    float xs[8] = {x0.x, x0.y, x0.z, x0.w, x1.x, x1.y, x1.z, x1.w};
    float wv[8] = {w0.x, w0.y, w0.z, w0.w, w1.x, w1.y, w1.z, w1.w};
    float bv[8] = {b0.x, b0.y, b0.z, b0.w, b1.x, b1.y, b1.z, b1.w};
    float rss = 0.0f, dt = 0.0f;
#pragma unroll
    for (int i = 0; i < 8; ++i) {
        float xn = xs[i] * xinv;
        float wn = wv[i] * winv;
        float d = xn - wn;
        float r = d - bv[i] * cs;
        rss += r * r;
        dt += xn * wn;
    }
#pragma unroll
    for (int m = 1; m < 64; m <<= 1) {
        rss += __shfl_xor(rss, m);
        dt += __shfl_xor(dt, m);
    }
    if (l == 0) {
        atomicAdd(&sums[0], sqrtf(rss));
        tlogit[row] = SCALE_F * dt;
    }
}

// ---------------- kernel B: normalize id_agent rows -> bf16 ----------------
__global__ void norm_w_kernel(const float* __restrict__ w,
                              ushort* __restrict__ wb) {
    int row = blockIdx.x * 4 + (threadIdx.x >> 6);
    int l = threadIdx.x & 63;
    const float4* rp = (const float4*)(w + (size_t)row * D_K);
    float4 a = rp[l], b = rp[64 + l];
    float ssq = dot4(a, a) + dot4(b, b);
#pragma unroll
    for (int m = 1; m < 64; m <<= 1) ssq += __shfl_xor(ssq, m);
    float inv = 1.0f / fmaxf(sqrtf(ssq), 1e-12f);
    a.x *= inv; a.y *= inv; a.z *= inv; a.w *= inv;
    b.x *= inv; b.y *= inv; b.z *= inv; b.w *= inv;
    ushort4 ua; ua.x = f2b(a.x); ua.y = f2b(a.y); ua.z = f2b(a.z); ua.w = f2b(a.w);
    ushort4 ub; ub.x = f2b(b.x); ub.y = f2b(b.y); ub.z = f2b(b.z); ub.w = f2b(b.w);
    ushort4* obp = (ushort4*)(wb + (size_t)row * D_K);
    obp[l] = ua; obp[64 + l] = ub;
}

// ------------- kernel C: bf16 MFMA GEMM, XCD-swizzled, XOR-swizzled LDS,
//               fixed-max sumexp epilogue with per-row atomic accumulate -------------
// Identical to the measured-best R4 kernel except __launch_bounds__(256,3):
// R4's (256,4) capped VGPR at 128 and the allocator settled at 64 — lean but
// serialized. (256,3) raises the cap (~170) so the scheduler can pipeline
// fragment loads (m97 runs 164 VGPR at 3 blocks/CU).
__global__ __launch_bounds__(256, 3) void gemm_lse_kernel(const ushort* __restrict__ A,
                                                          const ushort* __restrict__ W,
                                                          float* __restrict__ rowsum) {
    __shared__ ushort As[BM * BK];   // 16 KB, [row][8 slots of 16B], slots XOR-permuted
    __shared__ ushort Bs[BN * BK];   // 16 KB
    __shared__ float rs[2][BM];

    int tid = threadIdx.x;
    int wave = tid >> 6, l = tid & 63;
    int wm = wave >> 1, wn = wave & 1;

    // XCD-bijective swizzle: xcd = bid % 8 gets a contiguous chunk of tile-space
    // ordered (nt major, mt minor) so 8 blocks sharing a W-tile share one L2.
    int tile = (blockIdx.x & 7) * NT_ + (blockIdx.x >> 3);
    int nt = tile >> 3, mt = tile & 7;
    int m0 = mt * BM, n0 = nt * BN;

    int srow = l >> 3;                      // row 0..7 within an 8-row staging chunk
    int scol = ((l & 7) ^ (l >> 3)) * 8;    // pre-swizzled global slot (rule #21)

    f32x4 zero4 = {0.0f, 0.0f, 0.0f, 0.0f};
    f32x4 acc[4][4];
#pragma unroll
    for (int i = 0; i < 4; ++i)
#pragma unroll
        for (int j = 0; j < 4; ++j) acc[i][j] = zero4;

    int cl = l & 15, hi = l >> 4;

    for (int kt = 0; kt < D_K; kt += BK) {
#pragma unroll
        for (int i = 0; i < 4; ++i) {
            int rb = wave * 32 + i * 8;
            const ushort* ga = A + (size_t)(m0 + rb + srow) * D_K + kt + scol;
            __builtin_amdgcn_global_load_lds(
                (const __attribute__((address_space(1))) void*)ga,
                (__attribute__((address_space(3))) void*)&As[rb * BK], 16, 0, 0);
            int rn = n0 + rb + srow;
            rn = rn < C_N ? rn : C_N - 1;
            const ushort* gb = W + (size_t)rn * D_K + kt + scol;
            __builtin_amdgcn_global_load_lds(
                (const __attribute__((address_space(1))) void*)gb,
                (__attribute__((address_space(3))) void*)&Bs[rb * BK], 16, 0, 0);
        }
        __syncthreads();

#pragma unroll
        for (int kk = 0; kk < 2; ++kk) {
            // physical slot = logical slot (kk*4+hi) XOR (row&7); row&7 == cl&7
            int px = (((kk << 2) | hi) ^ (cl & 7)) * 8;
            short8 af[4], bfr[4];
#pragma unroll
            for (int mi = 0; mi < 4; ++mi)
                af[mi] = *(const short8*)&As[(wm * 64 + mi * 16 + cl) * BK + px];
#pragma unroll
            for (int ni = 0; ni < 4; ++ni)
                bfr[ni] = *(const short8*)&Bs[(wn * 64 + ni * 16 + cl) * BK + px];
#pragma unroll
            for (int mi = 0; mi < 4; ++mi)
#pragma unroll
                for (int ni = 0; ni < 4; ++ni)
                    acc[mi][ni] = __builtin_amdgcn_mfma_f32_16x16x32_bf16(af[mi], bfr[ni], acc[mi][ni], 0, 0, 0);
        }
        __syncthreads();
    }

    // epilogue: per-row sum of exp(s - 64); logits are cosines*64 so s <= 64 always
#pragma unroll
    for (int mi = 0; mi < 4; ++mi) {
#pragma unroll
        for (int j = 0; j < 4; ++j) {
            float se = 0.0f;
#pragma unroll
            for (int ni = 0; ni < 4; ++ni) {
                int cg = n0 + wn * 64 + ni * 16 + cl;
                if (cg < C_N) se += __expf(acc[mi][ni][j] * SCALE_F - MAXL);
            }
#pragma unroll
            for (int xm = 1; xm < 16; xm <<= 1) se += __shfl_xor(se, xm);
            if (cl == 0) rs[wn][wm * 64 + mi * 16 + hi * 4 + j] = se;
        }
    }
    __syncthreads();
    if (tid < BM) {
        float s = rs[0][tid] + rs[1][tid];
        atomicAdd(&rowsum[m0 + tid], s);
    }
}

// ------------- kernel D: merged row-finalize + scalar output (1 block, 1024 thr) -------------
__global__ void rowfin_final_kernel(const float* __restrict__ rowsum,
                                    const float* __restrict__ tlogit,
                                    const float* __restrict__ sums,
                                    float* __restrict__ out) {
    __shared__ float red[16];
    int tid = threadIdx.x;          // == row, 0..1023
    float lse = MAXL + logf(rowsum[tid]);
    float st = tlogit[tid];
    // replace exp(st) by exp(st - 64*margin) inside the lse
    float corr = __expf(st - lse) * (__expf(-SCALE_F * MARGIN_F) - 1.0f);
    float lse2 = lse + log1pf(corr);
    float nll = lse2 - (st - SCALE_F * MARGIN_F);
#pragma unroll
    for (int xm = 1; xm < 64; xm <<= 1) nll += __shfl_xor(nll, xm);
    if ((tid & 63) == 0) red[tid >> 6] = nll;
    __syncthreads();
    if (tid == 0) {
        float s = 0.0f;
#pragma unroll
        for (int i = 0; i < 16; ++i) s += red[i];
        float logp = s * (1.0f / B_N);
        float disc = sums[0] * (1.0f / B_N);
        float p = __expf(-logp);
        float om = 1.0f - p;
        out[0] = 0.4f * disc + om * om * logp;
    }
}

extern "C" void kernel_launch(void* const* d_in, const int* in_sizes, int n_in,
                              void* d_out, int out_size, void* d_ws, size_t ws_size,
                              hipStream_t stream) {
    const float* x = (const float*)d_in[0];
    const int* target = (const int*)d_in[1];
    const float* ida = (const float*)d_in[2];
    const float* bmat = (const float*)d_in[3];
    float* out = (float*)d_out;

    char* ws = (char*)d_ws;
    size_t off = 0;
    float* rowsum = (float*)(ws + off);  off += (size_t)B_N * 4;         // 4 KB
    float* sums = (float*)(ws + off);    off += 256;
    ushort* xnb = (ushort*)(ws + off);   off += (size_t)B_N * D_K * 2;   // 1 MB
    ushort* wbf = (ushort*)(ws + off);   off += (size_t)C_N * D_K * 2;   // 102.4 MB
    float* tlogit = (float*)(ws + off);  off += (size_t)B_N * 4;

    // zero rowsum + sums (contiguous region) every call — deterministic
    hipMemsetAsync(rowsum, 0, (size_t)B_N * 4 + 256, stream);

    normx_disc_kernel<<<B_N / 4, 256, 0, stream>>>(x, target, ida, bmat, xnb, sums, tlogit);
    norm_w_kernel<<<C_N / 4, 256, 0, stream>>>(ida, wbf);
    gemm_lse_kernel<<<MT_ * NT_, 256, 0, stream>>>(xnb, wbf, rowsum);
    rowfin_final_kernel<<<1, 1024, 0, stream>>>(rowsum, tlogit, sums, out);
}

// Round 9
// 149.411 us; speedup vs baseline: 1.6432x; 1.2961x over previous
//
#include <hip/hip_runtime.h>
#include <hip/hip_bf16.h>

typedef __attribute__((ext_vector_type(4))) int i32x4;

#define B_N 1024
#define D_K 512
#define C_N 100000
#define SCALE_F 64.0f
#define MARGIN_F 0.35f
#define BM 128
#define BN 128
#define BKB 128      // K-tile in BYTES per row (= 128 i8 elements)
#define NT_ 782      // ceil(100000/128)
#define MT_ 8        // 1024/128
#define MAXL 64.0f   // global logit bound: |cos|*64 <= 64 (+quant eps, harmless)
#define KQ (SCALE_F / (127.0f * 127.0f))   // logit = acc * sx * sw * KQ

__device__ __forceinline__ float dot4(float4 a, float4 b) {
    return a.x * b.x + a.y * b.y + a.z * b.z + a.w * b.w;
}
__device__ __forceinline__ float amax4(float4 a) {
    return fmaxf(fmaxf(fabsf(a.x), fabsf(a.y)), fmaxf(fabsf(a.z), fabsf(a.w)));
}
__device__ __forceinline__ int packq(float v0, float v1, float v2, float v3, float qs) {
    int q0 = __float2int_rn(v0 * qs), q1 = __float2int_rn(v1 * qs);
    int q2 = __float2int_rn(v2 * qs), q3 = __float2int_rn(v3 * qs);
    return (q0 & 0xFF) | ((q1 & 0xFF) << 8) | ((q2 & 0xFF) << 16) | ((q3 & 0xFF) << 24);
}

// ------- kernel A: fused norm_x -> i8 quantize + disc loss + exact target logit -------
__global__ void normx_disc_kernel(const float* __restrict__ x,
                                  const int* __restrict__ target,
                                  const float* __restrict__ ida,
                                  const float* __restrict__ bmat,
                                  char* __restrict__ xq,
                                  float* __restrict__ sx,
                                  float* __restrict__ sums,
                                  float* __restrict__ tlogit) {
    int row = blockIdx.x * 4 + (threadIdx.x >> 6);
    int l = threadIdx.x & 63;
    long t = (long)target[row];
    const float4* xp = (const float4*)(x + (size_t)row * D_K);
    const float4* wp = (const float4*)(ida + (size_t)t * D_K);
    const float4* bp = (const float4*)(bmat + (size_t)t * D_K);
    float4 x0 = xp[l], x1 = xp[64 + l];
    float4 w0 = wp[l], w1 = wp[64 + l];
    float4 b0 = bp[l], b1 = bp[64 + l];
    float xssq = dot4(x0, x0) + dot4(x1, x1);
    float wssq = dot4(w0, w0) + dot4(w1, w1);
    float bssq = dot4(b0, b0) + dot4(b1, b1);
    float xmx = fmaxf(amax4(x0), amax4(x1));
#pragma unroll
    for (int m = 1; m < 64; m <<= 1) {
        xssq += __shfl_xor(xssq, m);
        wssq += __shfl_xor(wssq, m);
        bssq += __shfl_xor(bssq, m);
        xmx = fmaxf(xmx, __shfl_xor(xmx, m));
    }
    float xinv = 1.0f / fmaxf(sqrtf(xssq), 1e-12f);
    float winv = 1.0f / fmaxf(sqrtf(wssq), 1e-12f);
    float btn = sqrtf(bssq);
    float cs = fminf(btn, 0.05f) / fmaxf(btn, 1e-12f);

    // quantize normalized x to i8 with per-row scale sxm = max|x_n|
    float sxm = fmaxf(xmx * xinv, 1e-12f);
    float qs = 127.0f / sxm * xinv;     // applied to RAW x
    int* oq = (int*)(xq + (size_t)row * D_K);
    oq[l] = packq(x0.x, x0.y, x0.z, x0.w, qs);
    oq[64 + l] = packq(x1.x, x1.y, x1.z, x1.w, qs);
    if (l == 0) sx[row] = sxm;

    float xs[8] = {x0.x, x0.y, x0.z, x0.w, x1.x, x1.y, x1.z, x1.w};
    float wv[8] = {w0.x, w0.y, w0.z, w0.w, w1.x, w1.y, w1.z, w1.w};
    float bv[8] = {b0.x, b0.y, b0.z, b0.w, b1.x, b1.y, b1.z, b1.w};
    float rss = 0.0f, dt = 0.0f;
#pragma unroll
    for (int i = 0; i < 8; ++i) {
        float xn = xs[i] * xinv;
        float wn = wv[i] * winv;
        float d = xn - wn;
        float r = d - bv[i] * cs;
        rss += r * r;
        dt += xn * wn;
    }
#pragma unroll
    for (int m = 1; m < 64; m <<= 1) {
        rss += __shfl_xor(rss, m);
        dt += __shfl_xor(dt, m);
    }
    if (l == 0) {
        atomicAdd(&sums[0], sqrtf(rss));
        tlogit[row] = SCALE_F * dt;
    }
}

// ---------------- kernel B: normalize id_agent rows -> i8 + per-row scale ----------------
__global__ void norm_w_kernel(const float* __restrict__ w,
                              char* __restrict__ wq,
                              float* __restrict__ sw) {
    int row = blockIdx.x * 4 + (threadIdx.x >> 6);
    int l = threadIdx.x & 63;
    const float4* rp = (const float4*)(w + (size_t)row * D_K);
    float4 a = rp[l], b = rp[64 + l];
    float ssq = dot4(a, a) + dot4(b, b);
    float mx = fmaxf(amax4(a), amax4(b));
#pragma unroll
    for (int m = 1; m < 64; m <<= 1) {
        ssq += __shfl_xor(ssq, m);
        mx = fmaxf(mx, __shfl_xor(mx, m));
    }
    float inv = 1.0f / fmaxf(sqrtf(ssq), 1e-12f);
    float swm = fmaxf(mx * inv, 1e-12f);
    float qs = 127.0f / swm * inv;      // applied to RAW w
    int* oq = (int*)(wq + (size_t)row * D_K);
    oq[l] = packq(a.x, a.y, a.z, a.w, qs);
    oq[64 + l] = packq(b.x, b.y, b.z, b.w, qs);
    if (l == 0) sw[row] = swm;
}

// ------------- kernel C: i8 MFMA GEMM (16x16x64_i8, 2x bf16 rate), XCD-swizzled,
//               XOR-swizzled LDS, fixed-max sumexp epilogue, per-row atomics -------------
// Byte-identical staging/swizzle structure to the measured-best R4 bf16 kernel:
// rows are 128 B (= 128 i8 = BK), 8 x 16B slots, phys_slot = logical ^ (row&7).
__global__ __launch_bounds__(256, 4) void gemm_lse_kernel(const char* __restrict__ A,
                                                          const char* __restrict__ W,
                                                          const float* __restrict__ sx,
                                                          const float* __restrict__ sw,
                                                          float* __restrict__ rowsum) {
    __shared__ char As[BM * BKB];   // 16 KB
    __shared__ char Bs[BN * BKB];   // 16 KB
    __shared__ float sxl[BM];
    __shared__ float swl[BN];
    __shared__ float rs[2][BM];

    int tid = threadIdx.x;
    int wave = tid >> 6, l = tid & 63;
    int wm = wave >> 1, wn = wave & 1;

    // XCD-bijective swizzle: xcd = bid % 8 gets a contiguous chunk of tile-space
    // ordered (nt major, mt minor) so 8 blocks sharing a W-tile share one L2.
    int tile = (blockIdx.x & 7) * NT_ + (blockIdx.x >> 3);
    int nt = tile >> 3, mt = tile & 7;
    int m0 = mt * BM, n0 = nt * BN;

    int srow = l >> 3;                       // row 0..7 within an 8-row staging chunk
    int scolB = ((l & 7) ^ (l >> 3)) * 16;   // pre-swizzled source byte slot (rule #21)

    // per-block scale tiles (ordered by the first __syncthreads below)
    if (tid < BM) {
        sxl[tid] = sx[m0 + tid];
        int c = n0 + tid;
        swl[tid] = sw[c < C_N ? c : C_N - 1];
    }

    i32x4 acc[4][4];
#pragma unroll
    for (int i = 0; i < 4; ++i)
#pragma unroll
        for (int j = 0; j < 4; ++j) acc[i][j] = (i32x4){0, 0, 0, 0};

    int cl = l & 15, hi = l >> 4;

    for (int kt = 0; kt < 4; ++kt) {         // 4 K-tiles of 128 i8
#pragma unroll
        for (int i = 0; i < 4; ++i) {
            int rb = wave * 32 + i * 8;
            const char* ga = A + (size_t)(m0 + rb + srow) * D_K + kt * BKB + scolB;
            __builtin_amdgcn_global_load_lds(
                (const __attribute__((address_space(1))) void*)ga,
                (__attribute__((address_space(3))) void*)&As[rb * BKB], 16, 0, 0);
            int rn = n0 + rb + srow;
            rn = rn < C_N ? rn : C_N - 1;
            const char* gb = W + (size_t)rn * D_K + kt * BKB + scolB;
            __builtin_amdgcn_global_load_lds(
                (const __attribute__((address_space(1))) void*)gb,
                (__attribute__((address_space(3))) void*)&Bs[rb * BKB], 16, 0, 0);
        }
        __syncthreads();

#pragma unroll
        for (int kk = 0; kk < 2; ++kk) {
            // physical slot = logical slot (kk*4+hi) XOR (row&7); row&7 == cl&7
            int px = (((kk << 2) | hi) ^ (cl & 7)) * 16;
            i32x4 af[4], bfr[4];
#pragma unroll
            for (int mi = 0; mi < 4; ++mi)
                af[mi] = *(const i32x4*)&As[(wm * 64 + mi * 16 + cl) * BKB + px];
#pragma unroll
            for (int ni = 0; ni < 4; ++ni)
                bfr[ni] = *(const i32x4*)&Bs[(wn * 64 + ni * 16 + cl) * BKB + px];
#pragma unroll
            for (int mi = 0; mi < 4; ++mi)
#pragma unroll
                for (int ni = 0; ni < 4; ++ni)
                    acc[mi][ni] = __builtin_amdgcn_mfma_i32_16x16x64_i8(af[mi], bfr[ni], acc[mi][ni], 0, 0, 0);
        }
        __syncthreads();
    }

    // epilogue: logit = acc * sx_row * sw_col * 64/127^2; per-row sum exp(s - 64)
    float frv[4][4], fcv[4];
#pragma unroll
    for (int mi = 0; mi < 4; ++mi)
#pragma unroll
        for (int j = 0; j < 4; ++j)
            frv[mi][j] = sxl[wm * 64 + mi * 16 + hi * 4 + j] * KQ;
#pragma unroll
    for (int ni = 0; ni < 4; ++ni)
        fcv[ni] = swl[wn * 64 + ni * 16 + cl];

#pragma unroll
    for (int mi = 0; mi < 4; ++mi) {
#pragma unroll
        for (int j = 0; j < 4; ++j) {
            float se = 0.0f;
#pragma unroll
            for (int ni = 0; ni < 4; ++ni) {
                int cg = n0 + wn * 64 + ni * 16 + cl;
                if (cg < C_N)
                    se += __expf((float)acc[mi][ni][j] * frv[mi][j] * fcv[ni] - MAXL);
            }
#pragma unroll
            for (int xm = 1; xm < 16; xm <<= 1) se += __shfl_xor(se, xm);
            if (cl == 0) rs[wn][wm * 64 + mi * 16 + hi * 4 + j] = se;
        }
    }
    __syncthreads();
    if (tid < BM) {
        float s = rs[0][tid] + rs[1][tid];
        atomicAdd(&rowsum[m0 + tid], s);
    }
}

// ------------- kernel D: merged row-finalize + scalar output (1 block, 1024 thr) -------------
__global__ void rowfin_final_kernel(const float* __restrict__ rowsum,
                                    const float* __restrict__ tlogit,
                                    const float* __restrict__ sums,
                                    float* __restrict__ out) {
    __shared__ float red[16];
    int tid = threadIdx.x;          // == row, 0..1023
    float lse = MAXL + logf(rowsum[tid]);
    float st = tlogit[tid];
    // replace exp(st) by exp(st - 64*margin) inside the lse
    float corr = __expf(st - lse) * (__expf(-SCALE_F * MARGIN_F) - 1.0f);
    float lse2 = lse + log1pf(corr);
    float nll = lse2 - (st - SCALE_F * MARGIN_F);
#pragma unroll
    for (int xm = 1; xm < 64; xm <<= 1) nll += __shfl_xor(nll, xm);
    if ((tid & 63) == 0) red[tid >> 6] = nll;
    __syncthreads();
    if (tid == 0) {
        float s = 0.0f;
#pragma unroll
        for (int i = 0; i < 16; ++i) s += red[i];
        float logp = s * (1.0f / B_N);
        float disc = sums[0] * (1.0f / B_N);
        float p = __expf(-logp);
        float om = 1.0f - p;
        out[0] = 0.4f * disc + om * om * logp;
    }
}

extern "C" void kernel_launch(void* const* d_in, const int* in_sizes, int n_in,
                              void* d_out, int out_size, void* d_ws, size_t ws_size,
                              hipStream_t stream) {
    const float* x = (const float*)d_in[0];
    const int* target = (const int*)d_in[1];
    const float* ida = (const float*)d_in[2];
    const float* bmat = (const float*)d_in[3];
    float* out = (float*)d_out;

    char* ws = (char*)d_ws;
    size_t off = 0;
    float* rowsum = (float*)(ws + off);  off += (size_t)B_N * 4;         // 4 KB
    float* sums = (float*)(ws + off);    off += 256;
    char* xq = (char*)(ws + off);        off += (size_t)B_N * D_K;       // 0.5 MB
    char* wq = (char*)(ws + off);        off += (size_t)C_N * D_K;       // 51.2 MB
    float* sx = (float*)(ws + off);      off += (size_t)B_N * 4;
    float* sw = (float*)(ws + off);      off += (size_t)C_N * 4;         // 0.4 MB
    float* tlogit = (float*)(ws + off);  off += (size_t)B_N * 4;

    // zero rowsum + sums (contiguous region) every call — deterministic
    hipMemsetAsync(rowsum, 0, (size_t)B_N * 4 + 256, stream);

    normx_disc_kernel<<<B_N / 4, 256, 0, stream>>>(x, target, ida, bmat, xq, sx, sums, tlogit);
    norm_w_kernel<<<C_N / 4, 256, 0, stream>>>(ida, wq, sw);
    gemm_lse_kernel<<<MT_ * NT_, 256, 0, stream>>>(xq, wq, sx, sw, rowsum);
    rowfin_final_kernel<<<1, 1024, 0, stream>>>(rowsum, tlogit, sums, out);
}